// Round 3
// baseline (526.105 us; speedup 1.0000x reference)
//
#include <hip/hip_runtime.h>
#include <hip/hip_bf16.h>

// Problem dims
#define BB 64
#define TT 128
#define FIN 12
#define HH 128
#define GG 512  // 4*H

#define LOG2E 1.4426950408889634f
#define TWO_LOG2E 2.8853900817779268f

typedef float f4 __attribute__((ext_vector_type(4)));

__device__ __forceinline__ float fexp2(float x) { return __builtin_amdgcn_exp2f(x); }
__device__ __forceinline__ float frcp(float x)  { return __builtin_amdgcn_rcpf(x); }

// tanh(x) = 1 - 2/(1+e^{2x}); correct limits at +/-inf via exp2->{inf,0}
__device__ __forceinline__ float tanh_f(float x) {
  return 1.0f - 2.0f * frcp(1.0f + fexp2(TWO_LOG2E * x));
}

// quad_perm broadcast of quad-lane L: ctrl = L*0b01010101
template <int CTRL>
__device__ __forceinline__ float quad_bcast(float v) {
  return __int_as_float(
      __builtin_amdgcn_update_dpp(0, __float_as_int(v), CTRL, 0xF, 0xF, true));
}

// lane^4 exchange via ds_swizzle (xor_mask=4): offset = (4<<10)|0x1F
__device__ __forceinline__ float swz_xor4(float v) {
  return __int_as_float(__builtin_amdgcn_ds_swizzle(__float_as_int(v), 0x101F));
}

#define FMA4S(acc, s, v) do { \
  acc.x = fmaf((s), (v).x, acc.x); \
  acc.y = fmaf((s), (v).y, acc.y); \
  acc.z = fmaf((s), (v).z, acc.z); \
  acc.w = fmaf((s), (v).w, acc.w); } while (0)

#define ACC4(hv, wv, a) do { \
  a = fmaf((hv).x, (wv).x, a); a = fmaf((hv).y, (wv).y, a); \
  a = fmaf((hv).z, (wv).z, a); a = fmaf((hv).w, (wv).w, a); } while (0)

// ---------------------------------------------------------------------------
// K1 v8: (gate, k-half, h) layout with asm-PINNED weight registers.
// v7 post-mortem: VGPR_Count=100 < the 128 needed for wr[32] -> compiler
// re-streamed Whh from L2 every step (sunk loads / spill).  v6 (VGPR=64,
// ~80 persistent floats needed) had the same disease.  Fix:
//  - 1024 threads (4 waves/SIMD keeps latency hiding), lane owns
//    (g = tid&3, p = (tid>>2)&1, i = tid>>3): 64-long half-dot, only
//    16 f4 + 2 f4 persistent weights per lane (72 VGPR) -> fits the
//    hard 128-VGPR cap of a 1024-thread block.
//  - volatile empty asm "+v" on every weight reg INSIDE the step loop:
//    values become opaque loop-carried registers; the compiler cannot
//    rematerialize them from memory.
//  - k-reduce = 1 ds_swizzle(xor4); gate gather = 3 quad_perm DPP
//    (quad == the 4 gates, absolute order); activation 1/lane; c,h
//    redundant per 8-lane group.  1 barrier/step; zero vm ops in loop.
// ---------------------------------------------------------------------------
__global__ __launch_bounds__(1024, 4) void lstm_kernel(
    const float* __restrict__ x,
    const float* __restrict__ eWih, const float* __restrict__ eWhh, const float* __restrict__ eb,
    const float* __restrict__ dWih, const float* __restrict__ dWhh, const float* __restrict__ db,
    float* __restrict__ encH, float* __restrict__ decH)
{
  const int b   = blockIdx.x;
  const int tid = threadIdx.x;
  const int g   = tid & 3;          // gate: 0=i 1=f 2=g 3=o
  const int p   = (tid >> 2) & 1;   // k-half
  const int i   = tid >> 3;         // h index 0..127

  __shared__ __align__(16) float xs[TT * FIN];     // 6 KB
  __shared__ __align__(16) float hbuf[2][HH];      // 1 KB, double-buffered h
  __shared__ __align__(16) float hist[64 * HH];    // 32 KB: 64-step h history

  if (tid < (TT * FIN / 4))
    ((float4*)xs)[tid] = ((const float4*)(x + (size_t)b * TT * FIN))[tid];
  if (tid < 256) ((float*)hbuf)[tid] = 0.0f;
  float c = 0.0f;  // redundant across the 8 (gate x k-half) lanes

  const bool  isg = (g == 2);
  const float mk  = isg ? TWO_LOG2E : -LOG2E;
  const int   ko  = p * 64;        // k-slice base
  const int   xo  = p ? 8 : 0;     // x-slice base (p=1 covers x[8..11] via zeros)

  int ts = 0;
  #pragma unroll 1
  for (int phase = 0; phase < 2; ++phase) {
    const float* Wih  = phase ? dWih : eWih;
    const float* Whh  = phase ? dWhh : eWhh;
    const float* bias = phase ? db : eb;
    float* Hout       = phase ? decH : encH;

    const int row = g * HH + i;
    const float* Wr = Whh + (size_t)row * HH + ko;
    f4 w0  = *(const f4*)(Wr + 0),  w1  = *(const f4*)(Wr + 4);
    f4 w2  = *(const f4*)(Wr + 8),  w3  = *(const f4*)(Wr + 12);
    f4 w4  = *(const f4*)(Wr + 16), w5  = *(const f4*)(Wr + 20);
    f4 w6  = *(const f4*)(Wr + 24), w7  = *(const f4*)(Wr + 28);
    f4 w8  = *(const f4*)(Wr + 32), w9  = *(const f4*)(Wr + 36);
    f4 w10 = *(const f4*)(Wr + 40), w11 = *(const f4*)(Wr + 44);
    f4 w12 = *(const f4*)(Wr + 48), w13 = *(const f4*)(Wr + 52);
    f4 w14 = *(const f4*)(Wr + 56), w15 = *(const f4*)(Wr + 60);

    // input weights: p=0 covers x[0..7], p=1 covers x[8..11] (+4 zeros)
    f4 wxa = *(const f4*)(Wih + row * FIN + xo);          // in-bounds for both p
    f4 wxb;
    if (p) { wxb.x = 0.f; wxb.y = 0.f; wxb.z = 0.f; wxb.w = 0.f; }
    else   { wxb = *(const f4*)(Wih + row * FIN + 4); }
    float bb_ = bias[row];

    #pragma unroll 1
    for (int half = 0; half < 2; ++half) {
      #pragma unroll 1
      for (int tt = 0; tt < 64; ++tt, ++ts) {
        const int t = half * 64 + tt;
        __syncthreads();  // h(t) ready in hbuf[ts&1]; hist copy reads done

        // pin weights in VGPRs: opaque loop-carried, cannot be re-loaded
        asm volatile("" : "+v"(w0), "+v"(w1), "+v"(w2), "+v"(w3),
                          "+v"(w4), "+v"(w5), "+v"(w6), "+v"(w7));
        asm volatile("" : "+v"(w8), "+v"(w9), "+v"(w10), "+v"(w11),
                          "+v"(w12), "+v"(w13), "+v"(w14), "+v"(w15),
                          "+v"(wxa), "+v"(wxb));

        const float* hb = hbuf[ts & 1] + ko;
        float a0 = 0.f, a1 = 0.f, a2 = 0.f, a3 = 0.f;
        {
          f4 h0 = *(const f4*)(hb + 0),  h1 = *(const f4*)(hb + 4);
          f4 h2 = *(const f4*)(hb + 8),  h3 = *(const f4*)(hb + 12);
          ACC4(h0, w0, a0); ACC4(h1, w1, a1); ACC4(h2, w2, a2); ACC4(h3, w3, a3);
        }
        {
          f4 h0 = *(const f4*)(hb + 16), h1 = *(const f4*)(hb + 20);
          f4 h2 = *(const f4*)(hb + 24), h3 = *(const f4*)(hb + 28);
          ACC4(h0, w4, a0); ACC4(h1, w5, a1); ACC4(h2, w6, a2); ACC4(h3, w7, a3);
        }
        {
          f4 h0 = *(const f4*)(hb + 32), h1 = *(const f4*)(hb + 36);
          f4 h2 = *(const f4*)(hb + 40), h3 = *(const f4*)(hb + 44);
          ACC4(h0, w8, a0); ACC4(h1, w9, a1); ACC4(h2, w10, a2); ACC4(h3, w11, a3);
        }
        {
          f4 h0 = *(const f4*)(hb + 48), h1 = *(const f4*)(hb + 52);
          f4 h2 = *(const f4*)(hb + 56), h3 = *(const f4*)(hb + 60);
          ACC4(h0, w12, a0); ACC4(h1, w13, a1); ACC4(h2, w14, a2); ACC4(h3, w15, a3);
        }

        // x contribution (broadcast LDS reads; p=1's second term is x zeros)
        const float* xt = xs + t * FIN;
        {
          f4 xva = *(const f4*)(xt + xo);
          f4 xvb = *(const f4*)(xt + 4);
          ACC4(xva, wxa, a0);
          ACC4(xvb, wxb, a1);
        }

        float a = (a0 + a1) + (a2 + a3);
        a += swz_xor4(a);           // + partner k-half (lane^4)
        a += bb_;

        // per-lane activation (one transcendental chain per lane)
        float r = frcp(1.0f + fexp2(mk * a));
        float z = isg ? fmaf(-2.0f, r, 1.0f) : r;

        // absolute gate gather within the quad (pure VALU)
        float zi = quad_bcast<0x00>(z);
        float zf = quad_bcast<0x55>(z);
        float zg = quad_bcast<0xAA>(z);
        float zo = quad_bcast<0xFF>(z);

        c = fmaf(zf, c, zi * zg);   // identical across the 8-lane group
        float hn = zo * tanh_f(c);
        if ((tid & 7) == 0) {
          hbuf[(ts + 1) & 1][i] = hn;   // 8 lanes/wave -> 8 distinct banks
          hist[tt * HH + i] = hn;       // LDS only -- no vm op in step loop
        }
      }
      // bulk-copy this half's history to global (64*128 floats = 2048 f4)
      __syncthreads();  // hist writes visible
      {
        float4* dst = (float4*)(Hout + ((size_t)b * TT + half * 64) * HH);
        const float4* src = (const float4*)hist;
        dst[tid]        = src[tid];
        dst[tid + 1024] = src[tid + 1024];
      }
      // next half's top-of-loop __syncthreads orders hist reuse; its vmcnt
      // drain absorbs the copy stores once per 64 steps.
    }
  }
}

// ---------------------------------------------------------------------------
// K2: A[b,s,h] = decH[b,s,:]·W1[h,:] + attn_b[h]   (m==0)
//     P[b,t,h] = encH[b,t,:]·W2[h,:]               (m==1)
// grid 1024 = (8 row-tiles x 64 b x 2 m), 256 threads, k-halved LDS W^T.
// ---------------------------------------------------------------------------
__global__ __launch_bounds__(256, 2) void proj_kernel(
    const float* __restrict__ encH, const float* __restrict__ decH,
    const float* __restrict__ attnW, const float* __restrict__ attnb,
    float* __restrict__ Abuf, float* __restrict__ Pbuf)
{
  const int m  = blockIdx.x & 1;
  const int b  = (blockIdx.x >> 1) & 63;
  const int r0 = (blockIdx.x >> 7) * 16;
  const int tid = threadIdx.x;

  __shared__ __align__(16) float WT[64 * 128];  // 32 KB: W^T for a k-half
  __shared__ __align__(16) float Xt[16 * 128];  // 8 KB

  const float* X = (m ? encH : decH) + ((size_t)b * TT + r0) * HH;
  const float* W = attnW + (m ? HH : 0);

  ((float4*)Xt)[tid]       = ((const float4*)X)[tid];
  ((float4*)Xt)[256 + tid] = ((const float4*)X)[256 + tid];

  const int hq = tid & 31, rr = tid >> 5;
  const int h0 = 4 * hq;

  float4 acc0, acc1;
  if (m == 0) { acc0 = *(const float4*)(attnb + h0); acc1 = acc0; }
  else        { acc0 = make_float4(0.f, 0.f, 0.f, 0.f); acc1 = acc0; }

  for (int kb = 0; kb < 2; ++kb) {
    __syncthreads();  // protect WT overwrite
    {
      int h = tid >> 1, koff = (tid & 1) * 32;
      #pragma unroll
      for (int j = 0; j < 8; ++j) {
        float4 v = *(const float4*)(W + h * 256 + kb * 64 + koff + 4 * j);
        int kp = koff + 4 * j;
        WT[(kp + 0) * 128 + h] = v.x;
        WT[(kp + 1) * 128 + h] = v.y;
        WT[(kp + 2) * 128 + h] = v.z;
        WT[(kp + 3) * 128 + h] = v.w;
      }
    }
    __syncthreads();
    const float* xr0 = Xt + (2 * rr) * 128 + kb * 64;
    const float* xr1 = xr0 + 128;
    #pragma unroll
    for (int k4 = 0; k4 < 64; k4 += 4) {
      float4 xa = *(const float4*)(xr0 + k4);
      float4 xb = *(const float4*)(xr1 + k4);
      float4 w0 = *(const float4*)&WT[(k4 + 0) * 128 + h0];
      float4 w1 = *(const float4*)&WT[(k4 + 1) * 128 + h0];
      float4 w2 = *(const float4*)&WT[(k4 + 2) * 128 + h0];
      float4 w3 = *(const float4*)&WT[(k4 + 3) * 128 + h0];
      FMA4S(acc0, xa.x, w0); FMA4S(acc0, xa.y, w1);
      FMA4S(acc0, xa.z, w2); FMA4S(acc0, xa.w, w3);
      FMA4S(acc1, xb.x, w0); FMA4S(acc1, xb.y, w1);
      FMA4S(acc1, xb.z, w2); FMA4S(acc1, xb.w, w3);
    }
  }
  float* O = (m ? Pbuf : Abuf) + ((size_t)b * TT + r0) * HH;
  *(float4*)(O + (2 * rr) * 128 + h0)     = acc0;
  *(float4*)(O + (2 * rr + 1) * 128 + h0) = acc1;
}

// ---------------------------------------------------------------------------
// K3: attention + output. Block = (b, 16 decoder steps). 512 threads.
// t halved so LDS stays < 64 KB; P transposed into LDS with XOR-quad swizzle.
// ---------------------------------------------------------------------------
__global__ __launch_bounds__(512, 2) void attn_kernel(
    const float* __restrict__ encH, const float* __restrict__ decH,
    const float* __restrict__ Abuf, const float* __restrict__ Pbuf,
    const float* __restrict__ vw, const float* __restrict__ outW,
    const float* __restrict__ outb, float* __restrict__ out)
{
  const int b  = blockIdx.x >> 3;
  const int s0 = (blockIdx.x & 7) * 16;
  const int tid = threadIdx.x;

  __shared__ __align__(16) float buf[64 * 128];    // 32 KB: P^T-half (swizzled), later encH-half
  __shared__ __align__(16) float a_lds[16 * 128];  // 8 KB: A tile, later ctx
  __shared__ __align__(16) float sc[16 * 128];     // 8 KB: scores -> weights
  __shared__ __align__(16) float dh[16 * 128];     // 8 KB: decH tile
  __shared__ __align__(16) float vl[HH];

  ((float4*)a_lds)[tid] = ((const float4*)(Abuf + ((size_t)b * TT + s0) * HH))[tid];
  ((float4*)dh)[tid]    = ((const float4*)(decH + ((size_t)b * TT + s0) * HH))[tid];
  if (tid < 32) ((float4*)vl)[tid] = ((const float4*)vw)[tid];

  const int u  = tid & 31;
  const int sl = tid >> 5;   // 0..15 decoder-step within tile
  const int uq = u & 15;     // t-quad within half
  const int uh = u >> 4;     // 0/1 h-half

  // ---- energies/scores ----
  for (int half = 0; half < 2; ++half) {
    const int tbase = half * 64;
    __syncthreads();  // prev buf use done (also covers initial staging)
    #pragma unroll
    for (int i = 0; i < 4; ++i) {
      int flat = i * 2048 + tid * 4;
      int tp = flat >> 7;        // 0..63
      int h0 = flat & 127;
      float4 v = *(const float4*)(Pbuf + ((size_t)b * TT + tbase + tp) * HH + h0);
      int tq = tp >> 2, tr = tp & 3;
      buf[(h0 + 0) * 64 + 4 * ((tq ^ ((h0 + 0) >> 2)) & 15) + tr] = v.x;
      buf[(h0 + 1) * 64 + 4 * ((tq ^ ((h0 + 1) >> 2)) & 15) + tr] = v.y;
      buf[(h0 + 2) * 64 + 4 * ((tq ^ ((h0 + 2) >> 2)) & 15) + tr] = v.z;
      buf[(h0 + 3) * 64 + 4 * ((tq ^ ((h0 + 3) >> 2)) & 15) + tr] = v.w;
    }
    __syncthreads();
    float4 acc = make_float4(0.f, 0.f, 0.f, 0.f);
    const float* arow = a_lds + sl * 128;
    #pragma unroll 8
    for (int hh = 0; hh < 64; ++hh) {
      int h = uh * 64 + hh;
      float ah = arow[h];
      float vh = vl[h];
      float4 p4 = *(const float4*)&buf[h * 64 + 4 * ((uq ^ ((h >> 2) & 15)) & 15)];
      acc.x = fmaf(vh, tanh_f(ah + p4.x), acc.x);
      acc.y = fmaf(vh, tanh_f(ah + p4.y), acc.y);
      acc.z = fmaf(vh, tanh_f(ah + p4.z), acc.z);
      acc.w = fmaf(vh, tanh_f(ah + p4.w), acc.w);
    }
    acc.x += __shfl_xor(acc.x, 16, 64);
    acc.y += __shfl_xor(acc.y, 16, 64);
    acc.z += __shfl_xor(acc.z, 16, 64);
    acc.w += __shfl_xor(acc.w, 16, 64);
    if (uh == 0) *(float4*)&sc[sl * 128 + tbase + 4 * uq] = acc;
  }
  __syncthreads();

  // ---- softmax over t (per s row; 32 lanes x f4 = 128) ----
  {
    float4 sv = *(const float4*)&sc[sl * 128 + 4 * u];
    float mx = fmaxf(fmaxf(sv.x, sv.y), fmaxf(sv.z, sv.w));
    #pragma unroll
    for (int msk = 1; msk <= 16; msk <<= 1) mx = fmaxf(mx, __shfl_xor(mx, msk, 64));
    float4 e;
    e.x = fexp2(LOG2E * (sv.x - mx));
    e.y = fexp2(LOG2E * (sv.y - mx));
    e.z = fexp2(LOG2E * (sv.z - mx));
    e.w = fexp2(LOG2E * (sv.w - mx));
    float sm = (e.x + e.y) + (e.z + e.w);
    #pragma unroll
    for (int msk = 1; msk <= 16; msk <<= 1) sm += __shfl_xor(sm, msk, 64);
    float r = frcp(sm);
    e.x *= r; e.y *= r; e.z *= r; e.w *= r;
    *(float4*)&sc[sl * 128 + 4 * u] = e;
  }

  // ---- ctx = w @ encH ----
  float4 ctx = make_float4(0.f, 0.f, 0.f, 0.f);
  const int h0c = 4 * u;
  for (int half = 0; half < 2; ++half) {
    const int tbase = half * 64;
    __syncthreads();  // buf reuse; also orders softmax writes before reads
    #pragma unroll
    for (int i = 0; i < 4; ++i) {
      int flat = i * 2048 + tid * 4;
      int tp = flat >> 7;
      int hh0 = flat & 127;
      *(float4*)&buf[tp * 128 + hh0] =
          *(const float4*)(encH + ((size_t)b * TT + tbase + tp) * HH + hh0);
    }
    __syncthreads();
    const float* wrow = sc + sl * 128 + tbase;
    #pragma unroll 8
    for (int tp = 0; tp < 64; ++tp) {
      float wt = wrow[tp];
      float4 e4 = *(const float4*)&buf[tp * 128 + h0c];
      FMA4S(ctx, wt, e4);
    }
  }
  __syncthreads();
  *(float4*)&a_lds[sl * 128 + h0c] = ctx;  // overlay A tile with ctx
  __syncthreads();

  // ---- out = [decH, ctx] @ outW^T + outb ----
  if (tid < 192) {
    int s = tid / 12, f = tid % 12;
    float acc = outb[f];
    const float4* w4 = (const float4*)(outW + f * 256);
    const float4* d4 = (const float4*)(dh + s * 128);
    const float4* c4 = (const float4*)(a_lds + s * 128);
    #pragma unroll
    for (int k = 0; k < 32; ++k) {
      float4 wv = w4[k], dv = d4[k];
      acc = fmaf(wv.x, dv.x, acc); acc = fmaf(wv.y, dv.y, acc);
      acc = fmaf(wv.z, dv.z, acc); acc = fmaf(wv.w, dv.w, acc);
    }
    #pragma unroll
    for (int k = 0; k < 32; ++k) {
      float4 wv = w4[32 + k], cv = c4[k];
      acc = fmaf(wv.x, cv.x, acc); acc = fmaf(wv.y, cv.y, acc);
      acc = fmaf(wv.z, cv.z, acc); acc = fmaf(wv.w, cv.w, acc);
    }
    out[((size_t)b * TT + s0 + s) * FIN + f] = acc;
  }
}

// ---------------------------------------------------------------------------
extern "C" void kernel_launch(void* const* d_in, const int* in_sizes, int n_in,
                              void* d_out, int out_size, void* d_ws, size_t ws_size,
                              hipStream_t stream)
{
  const float* x     = (const float*)d_in[0];
  const float* eWih  = (const float*)d_in[1];
  const float* eWhh  = (const float*)d_in[2];
  const float* eb    = (const float*)d_in[3];
  const float* dWih  = (const float*)d_in[4];
  const float* dWhh  = (const float*)d_in[5];
  const float* db    = (const float*)d_in[6];
  const float* attnW = (const float*)d_in[7];
  const float* attnb = (const float*)d_in[8];
  const float* vw    = (const float*)d_in[9];
  const float* outW  = (const float*)d_in[10];
  const float* outb  = (const float*)d_in[11];
  float* out = (float*)d_out;

  float* ws   = (float*)d_ws;
  const size_t SEG = (size_t)BB * TT * HH;  // 1,048,576 floats = 4 MB
  float* encH = ws;
  float* decH = ws + SEG;
  float* Abuf = ws + 2 * SEG;
  float* Pbuf = ws + 3 * SEG;

  lstm_kernel<<<64, 1024, 0, stream>>>(x, eWih, eWhh, eb, dWih, dWhh, db, encH, decH);
  proj_kernel<<<1024, 256, 0, stream>>>(encH, decH, attnW, attnb, Abuf, Pbuf);
  attn_kernel<<<512, 512, 0, stream>>>(encH, decH, Abuf, Pbuf, vw, outW, outb, out);
}

// Round 4
// 322.348 us; speedup vs baseline: 1.6321x; 1.6321x over previous
//
#include <hip/hip_runtime.h>
#include <hip/hip_bf16.h>

// Problem dims
#define BB 64
#define TT 128
#define FIN 12
#define HH 128
#define GG 512  // 4*H

#define LOG2E 1.4426950408889634f
#define TWO_LOG2E 2.8853900817779268f

__device__ __forceinline__ float fexp2(float x) { return __builtin_amdgcn_exp2f(x); }
__device__ __forceinline__ float frcp(float x)  { return __builtin_amdgcn_rcpf(x); }

// tanh(x) = 1 - 2/(1+e^{2x}); correct limits at +/-inf via exp2->{inf,0}
__device__ __forceinline__ float tanh_f(float x) {
  return 1.0f - 2.0f * frcp(1.0f + fexp2(TWO_LOG2E * x));
}
__device__ __forceinline__ float sigm_f(float x) {
  return frcp(1.0f + fexp2(-LOG2E * x));
}

// DPP 8-lane sum (over lane bits 0..2): xor1 + xor2 via quad_perm, then
// lane^7 via row_half_mirror. Pure VALU -- no DS-pipe traffic.
template <int CTRL>
__device__ __forceinline__ float dpp_addstage(float v) {
  int s = __builtin_amdgcn_update_dpp(0, __float_as_int(v), CTRL, 0xF, 0xF, true);
  return v + __int_as_float(s);
}
__device__ __forceinline__ float red8(float v) {
  v = dpp_addstage<0xB1>(v);   // quad_perm [1,0,3,2]: partner lane^1
  v = dpp_addstage<0x4E>(v);   // quad_perm [2,3,0,1]: partner lane^2
  v = dpp_addstage<0x141>(v);  // row_half_mirror: partner lane^7 -> 8-lane total
  return v;
}

#define FMA4S(acc, s, v) do { \
  acc.x = fmaf((s), (v).x, acc.x); \
  acc.y = fmaf((s), (v).y, acc.y); \
  acc.z = fmaf((s), (v).z, acc.z); \
  acc.w = fmaf((s), (v).w, acc.w); } while (0)

#define ACC4(hv, wv, a) do { \
  a = fmaf((hv).x, (wv).x, a); a = fmaf((hv).y, (wv).y, a); \
  a = fmaf((hv).z, (wv).z, a); a = fmaf((hv).w, (wv).w, a); } while (0)

// ---------------------------------------------------------------------------
// K1 = v6 EXACT REVERT (measured 206.9us, round 0).  v7/v8 post-mortem:
// VALUBusy is averaged over all 256 CUs; with 64 active CUs v6 runs at
// ~108% local VALU issue -- it is issue-bound, and the weight re-stream is
// only a ~15% slice.  Register-pinning attempts spilled to scratch (v8) or
// halved latency hiding (v7).  Keep v6.
// ---------------------------------------------------------------------------
__global__ __launch_bounds__(1024, 4) void lstm_kernel(
    const float* __restrict__ x,
    const float* __restrict__ eWih, const float* __restrict__ eWhh, const float* __restrict__ eb,
    const float* __restrict__ dWih, const float* __restrict__ dWhh, const float* __restrict__ db,
    float* __restrict__ encH, float* __restrict__ decH)
{
  const int b   = blockIdx.x;
  const int tid = threadIdx.x;
  const int q   = tid & 7;    // k-slice index
  const int i   = tid >> 3;   // h index 0..127

  __shared__ __align__(16) float xs[TT * FIN];     // 6 KB
  __shared__ __align__(16) float hbuf[2][160];     // skewed h, double-buffered
  __shared__ __align__(16) float hist[64 * HH];    // 32 KB: 64-step h history

  if (tid < (TT * FIN / 4))
    ((float4*)xs)[tid] = ((const float4*)(x + (size_t)b * TT * FIN))[tid];
  if (tid < 320) ((float*)hbuf)[tid] = 0.0f;
  float c = 0.0f;  // live in q==0 lanes

  const int xo   = (q < 4) ? 3 * q : 0;   // in-bounds x offset
  const float xz = (q < 4) ? 1.0f : 0.0f;

  int ts = 0;
  #pragma unroll 1
  for (int phase = 0; phase < 2; ++phase) {
    const float* Wih  = phase ? dWih : eWih;
    const float* Whh  = phase ? dWhh : eWhh;
    const float* bias = phase ? db : eb;
    float* Hout       = phase ? decH : encH;

    // recurrent weights: 4 gates x 16 k (k = 16q + 4j + comp)
    float4 wg[4][4];
    #pragma unroll
    for (int g = 0; g < 4; ++g)
      #pragma unroll
      for (int j = 0; j < 4; ++j)
        wg[g][j] = *(const float4*)(Whh + ((g * HH + i) * HH) + 16 * q + 4 * j);

    // input weights: 3 columns (xo..xo+2) of each gate row; zero for q>=4
    float wx[4][3];
    #pragma unroll
    for (int g = 0; g < 4; ++g)
      #pragma unroll
      for (int j = 0; j < 3; ++j)
        wx[g][j] = Wih[(g * HH + i) * FIN + xo + j] * xz;

    const float bi = bias[i], bf = bias[HH + i], bg = bias[2 * HH + i], bo = bias[3 * HH + i];

    #pragma unroll 1
    for (int half = 0; half < 2; ++half) {
      #pragma unroll 1
      for (int tt = 0; tt < 64; ++tt, ++ts) {
        const int t = half * 64 + tt;
        __syncthreads();  // h(t) ready in hbuf[ts&1]; hist copy reads done
        const float* hb = hbuf[ts & 1] + q * 20;
        float4 h0 = *(const float4*)(hb + 0);
        float4 h1 = *(const float4*)(hb + 4);
        float4 h2 = *(const float4*)(hb + 8);
        float4 h3 = *(const float4*)(hb + 12);

        // x contribution (q<4 lanes carry it; others have zero weights)
        const float* xt = xs + t * FIN + xo;
        float x0 = xt[0], x1 = xt[1], x2 = xt[2];
        float ai = wx[0][0] * x0 + wx[0][1] * x1 + wx[0][2] * x2;
        float af = wx[1][0] * x0 + wx[1][1] * x1 + wx[1][2] * x2;
        float ag = wx[2][0] * x0 + wx[2][1] * x1 + wx[2][2] * x2;
        float ao = wx[3][0] * x0 + wx[3][1] * x1 + wx[3][2] * x2;

        ACC4(h0, wg[0][0], ai); ACC4(h0, wg[1][0], af); ACC4(h0, wg[2][0], ag); ACC4(h0, wg[3][0], ao);
        ACC4(h1, wg[0][1], ai); ACC4(h1, wg[1][1], af); ACC4(h1, wg[2][1], ag); ACC4(h1, wg[3][1], ao);
        ACC4(h2, wg[0][2], ai); ACC4(h2, wg[1][2], af); ACC4(h2, wg[2][2], ag); ACC4(h2, wg[3][2], ao);
        ACC4(h3, wg[0][3], ai); ACC4(h3, wg[1][3], af); ACC4(h3, wg[2][3], ag); ACC4(h3, wg[3][3], ao);

        // reduce partials across the 8 q-lanes -- pure DPP (VALU)
        ai = red8(ai); af = red8(af); ag = red8(ag); ao = red8(ao);

        if (q == 0) {
          float zi = sigm_f(ai + bi);
          float zf = sigm_f(af + bf);
          float zg = tanh_f(ag + bg);
          float zo = sigm_f(ao + bo);
          c = fmaf(zf, c, zi * zg);
          float hn = zo * tanh_f(c);
          hbuf[(ts + 1) & 1][(i >> 4) * 20 + (i & 15)] = hn;
          hist[tt * HH + i] = hn;   // LDS only -- no vm op in the step loop
        }
      }
      // bulk-copy this half's history to global (64*128 floats = 2048 f4)
      __syncthreads();  // hist writes visible
      {
        float4* dst = (float4*)(Hout + ((size_t)b * TT + half * 64) * HH);
        const float4* src = (const float4*)hist;
        dst[tid]        = src[tid];
        dst[tid + 1024] = src[tid + 1024];
      }
      // next half's top-of-loop __syncthreads orders hist reuse; its vmcnt
      // drain absorbs the copy stores once per 64 steps.
    }
  }
}

// ---------------------------------------------------------------------------
// K2: A[b,s,h] = decH[b,s,:]·W1[h,:] + attn_b[h]   (m==0)
//     P[b,t,h] = encH[b,t,:]·W2[h,:]               (m==1)
// grid 1024 = (8 row-tiles x 64 b x 2 m), 256 threads, k-halved LDS W^T.
// ---------------------------------------------------------------------------
__global__ __launch_bounds__(256, 2) void proj_kernel(
    const float* __restrict__ encH, const float* __restrict__ decH,
    const float* __restrict__ attnW, const float* __restrict__ attnb,
    float* __restrict__ Abuf, float* __restrict__ Pbuf)
{
  const int m  = blockIdx.x & 1;
  const int b  = (blockIdx.x >> 1) & 63;
  const int r0 = (blockIdx.x >> 7) * 16;
  const int tid = threadIdx.x;

  __shared__ __align__(16) float WT[64 * 128];  // 32 KB: W^T for a k-half
  __shared__ __align__(16) float Xt[16 * 128];  // 8 KB

  const float* X = (m ? encH : decH) + ((size_t)b * TT + r0) * HH;
  const float* W = attnW + (m ? HH : 0);

  ((float4*)Xt)[tid]       = ((const float4*)X)[tid];
  ((float4*)Xt)[256 + tid] = ((const float4*)X)[256 + tid];

  const int hq = tid & 31, rr = tid >> 5;
  const int h0 = 4 * hq;

  float4 acc0, acc1;
  if (m == 0) { acc0 = *(const float4*)(attnb + h0); acc1 = acc0; }
  else        { acc0 = make_float4(0.f, 0.f, 0.f, 0.f); acc1 = acc0; }

  for (int kb = 0; kb < 2; ++kb) {
    __syncthreads();  // protect WT overwrite
    {
      int h = tid >> 1, koff = (tid & 1) * 32;
      #pragma unroll
      for (int j = 0; j < 8; ++j) {
        float4 v = *(const float4*)(W + h * 256 + kb * 64 + koff + 4 * j);
        int kp = koff + 4 * j;
        WT[(kp + 0) * 128 + h] = v.x;
        WT[(kp + 1) * 128 + h] = v.y;
        WT[(kp + 2) * 128 + h] = v.z;
        WT[(kp + 3) * 128 + h] = v.w;
      }
    }
    __syncthreads();
    const float* xr0 = Xt + (2 * rr) * 128 + kb * 64;
    const float* xr1 = xr0 + 128;
    #pragma unroll
    for (int k4 = 0; k4 < 64; k4 += 4) {
      float4 xa = *(const float4*)(xr0 + k4);
      float4 xb = *(const float4*)(xr1 + k4);
      float4 w0 = *(const float4*)&WT[(k4 + 0) * 128 + h0];
      float4 w1 = *(const float4*)&WT[(k4 + 1) * 128 + h0];
      float4 w2 = *(const float4*)&WT[(k4 + 2) * 128 + h0];
      float4 w3 = *(const float4*)&WT[(k4 + 3) * 128 + h0];
      FMA4S(acc0, xa.x, w0); FMA4S(acc0, xa.y, w1);
      FMA4S(acc0, xa.z, w2); FMA4S(acc0, xa.w, w3);
      FMA4S(acc1, xb.x, w0); FMA4S(acc1, xb.y, w1);
      FMA4S(acc1, xb.z, w2); FMA4S(acc1, xb.w, w3);
    }
  }
  float* O = (m ? Pbuf : Abuf) + ((size_t)b * TT + r0) * HH;
  *(float4*)(O + (2 * rr) * 128 + h0)     = acc0;
  *(float4*)(O + (2 * rr + 1) * 128 + h0) = acc1;
}

// ---------------------------------------------------------------------------
// K3 v2: attention + output.  Changes vs v1:
//  (a) tanh factorization: tanh(a+p) = 1 - 2/(1 + e^{2a} e^{2p}).
//      Stage Ep = exp2(2log2e*P) (transposed+swizzled) and Ea = exp2(2log2e*A)
//      once; the energy inner loop is then {fma, rcp, fma} per element --
//      one trans op instead of two, no exp2 in the hot loop.  The constant
//      sum(v) term cancels under softmax over t, so sc = -2 * sum(v*r).
//  (b) a_lds and sc padded to row stride 132 (128 = 0 mod 32 banks gave
//      16-way same-bank conflicts on every per-h / per-t scalar read).
//  (c) Ea / v read as float4 (one b128 per 4 h instead of 8 b32).
// ---------------------------------------------------------------------------
#define AST 132  // padded row stride for a_lds / sc

__global__ __launch_bounds__(512, 2) void attn_kernel(
    const float* __restrict__ encH, const float* __restrict__ decH,
    const float* __restrict__ Abuf, const float* __restrict__ Pbuf,
    const float* __restrict__ vw, const float* __restrict__ outW,
    const float* __restrict__ outb, float* __restrict__ out)
{
  const int b  = blockIdx.x >> 3;
  const int s0 = (blockIdx.x & 7) * 16;
  const int tid = threadIdx.x;

  __shared__ __align__(16) float buf[64 * 128];    // 32 KB: Ep^T-half (swizzled), later encH-half
  __shared__ __align__(16) float a_lds[16 * AST];  // 8.25 KB: Ea tile, later ctx
  __shared__ __align__(16) float sc[16 * AST];     // 8.25 KB: scores -> weights
  __shared__ __align__(16) float dh[16 * 128];     // 8 KB: decH tile
  __shared__ __align__(16) float vl[HH];

  {
    // Ea = exp2(2log2e * A) into padded a_lds
    int r = tid >> 5, c4 = (tid & 31) * 4;
    float4 av = *(const float4*)(Abuf + ((size_t)b * TT + s0 + r) * HH + c4);
    av.x = fexp2(TWO_LOG2E * av.x);
    av.y = fexp2(TWO_LOG2E * av.y);
    av.z = fexp2(TWO_LOG2E * av.z);
    av.w = fexp2(TWO_LOG2E * av.w);
    *(float4*)&a_lds[r * AST + c4] = av;
  }
  ((float4*)dh)[tid] = ((const float4*)(decH + ((size_t)b * TT + s0) * HH))[tid];
  if (tid < 32) ((float4*)vl)[tid] = ((const float4*)vw)[tid];

  const int u  = tid & 31;
  const int sl = tid >> 5;   // 0..15 decoder-step within tile
  const int uq = u & 15;     // t-quad within half
  const int uh = u >> 4;     // 0/1 h-half

  // ---- energies/scores ----
  for (int half = 0; half < 2; ++half) {
    const int tbase = half * 64;
    __syncthreads();  // prev buf use done (also covers initial staging)
    #pragma unroll
    for (int i = 0; i < 4; ++i) {
      int flat = i * 2048 + tid * 4;
      int tp = flat >> 7;        // 0..63
      int h0 = flat & 127;
      float4 v = *(const float4*)(Pbuf + ((size_t)b * TT + tbase + tp) * HH + h0);
      v.x = fexp2(TWO_LOG2E * v.x);
      v.y = fexp2(TWO_LOG2E * v.y);
      v.z = fexp2(TWO_LOG2E * v.z);
      v.w = fexp2(TWO_LOG2E * v.w);
      int tq = tp >> 2, tr = tp & 3;
      buf[(h0 + 0) * 64 + 4 * ((tq ^ ((h0 + 0) >> 2)) & 15) + tr] = v.x;
      buf[(h0 + 1) * 64 + 4 * ((tq ^ ((h0 + 1) >> 2)) & 15) + tr] = v.y;
      buf[(h0 + 2) * 64 + 4 * ((tq ^ ((h0 + 2) >> 2)) & 15) + tr] = v.z;
      buf[(h0 + 3) * 64 + 4 * ((tq ^ ((h0 + 3) >> 2)) & 15) + tr] = v.w;
    }
    __syncthreads();
    float4 acc = make_float4(0.f, 0.f, 0.f, 0.f);
    const float* earow = a_lds + sl * AST;
    #pragma unroll 4
    for (int hh = 0; hh < 64; hh += 4) {
      const int h = uh * 64 + hh;
      float4 ea = *(const float4*)&earow[h];
      float4 va = *(const float4*)&vl[h];
      const int xoff = 4 * ((uq ^ ((h >> 2) & 15)) & 15);  // same for h..h+3
      float4 p0 = *(const float4*)&buf[(h + 0) * 64 + xoff];
      float4 p1 = *(const float4*)&buf[(h + 1) * 64 + xoff];
      float4 p2 = *(const float4*)&buf[(h + 2) * 64 + xoff];
      float4 p3 = *(const float4*)&buf[(h + 3) * 64 + xoff];
      acc.x = fmaf(va.x, frcp(fmaf(ea.x, p0.x, 1.f)), acc.x);
      acc.y = fmaf(va.x, frcp(fmaf(ea.x, p0.y, 1.f)), acc.y);
      acc.z = fmaf(va.x, frcp(fmaf(ea.x, p0.z, 1.f)), acc.z);
      acc.w = fmaf(va.x, frcp(fmaf(ea.x, p0.w, 1.f)), acc.w);
      acc.x = fmaf(va.y, frcp(fmaf(ea.y, p1.x, 1.f)), acc.x);
      acc.y = fmaf(va.y, frcp(fmaf(ea.y, p1.y, 1.f)), acc.y);
      acc.z = fmaf(va.y, frcp(fmaf(ea.y, p1.z, 1.f)), acc.z);
      acc.w = fmaf(va.y, frcp(fmaf(ea.y, p1.w, 1.f)), acc.w);
      acc.x = fmaf(va.z, frcp(fmaf(ea.z, p2.x, 1.f)), acc.x);
      acc.y = fmaf(va.z, frcp(fmaf(ea.z, p2.y, 1.f)), acc.y);
      acc.z = fmaf(va.z, frcp(fmaf(ea.z, p2.z, 1.f)), acc.z);
      acc.w = fmaf(va.z, frcp(fmaf(ea.z, p2.w, 1.f)), acc.w);
      acc.x = fmaf(va.w, frcp(fmaf(ea.w, p3.x, 1.f)), acc.x);
      acc.y = fmaf(va.w, frcp(fmaf(ea.w, p3.y, 1.f)), acc.y);
      acc.z = fmaf(va.w, frcp(fmaf(ea.w, p3.z, 1.f)), acc.z);
      acc.w = fmaf(va.w, frcp(fmaf(ea.w, p3.w, 1.f)), acc.w);
    }
    acc.x += __shfl_xor(acc.x, 16, 64);
    acc.y += __shfl_xor(acc.y, 16, 64);
    acc.z += __shfl_xor(acc.z, 16, 64);
    acc.w += __shfl_xor(acc.w, 16, 64);
    if (uh == 0) {
      float4 o;
      o.x = -2.f * acc.x; o.y = -2.f * acc.y;
      o.z = -2.f * acc.z; o.w = -2.f * acc.w;
      *(float4*)&sc[sl * AST + tbase + 4 * uq] = o;
    }
  }
  __syncthreads();

  // ---- softmax over t (per s row; 32 lanes x f4 = 128) ----
  {
    float4 sv = *(const float4*)&sc[sl * AST + 4 * u];
    float mx = fmaxf(fmaxf(sv.x, sv.y), fmaxf(sv.z, sv.w));
    #pragma unroll
    for (int msk = 1; msk <= 16; msk <<= 1) mx = fmaxf(mx, __shfl_xor(mx, msk, 64));
    float4 e;
    e.x = fexp2(LOG2E * (sv.x - mx));
    e.y = fexp2(LOG2E * (sv.y - mx));
    e.z = fexp2(LOG2E * (sv.z - mx));
    e.w = fexp2(LOG2E * (sv.w - mx));
    float sm = (e.x + e.y) + (e.z + e.w);
    #pragma unroll
    for (int msk = 1; msk <= 16; msk <<= 1) sm += __shfl_xor(sm, msk, 64);
    float r = frcp(sm);
    e.x *= r; e.y *= r; e.z *= r; e.w *= r;
    *(float4*)&sc[sl * AST + 4 * u] = e;
  }

  // ---- ctx = w @ encH ----
  float4 ctx = make_float4(0.f, 0.f, 0.f, 0.f);
  const int h0c = 4 * u;
  for (int half = 0; half < 2; ++half) {
    const int tbase = half * 64;
    __syncthreads();  // buf reuse; also orders softmax writes before reads
    #pragma unroll
    for (int i = 0; i < 4; ++i) {
      int flat = i * 2048 + tid * 4;
      int tp = flat >> 7;
      int hh0 = flat & 127;
      *(float4*)&buf[tp * 128 + hh0] =
          *(const float4*)(encH + ((size_t)b * TT + tbase + tp) * HH + hh0);
    }
    __syncthreads();
    const float* wrow = sc + sl * AST + tbase;
    #pragma unroll 8
    for (int tp = 0; tp < 64; ++tp) {
      float wt = wrow[tp];
      float4 e4 = *(const float4*)&buf[tp * 128 + h0c];
      FMA4S(ctx, wt, e4);
    }
  }
  __syncthreads();
  *(float4*)&a_lds[sl * AST + h0c] = ctx;  // overlay Ea tile with ctx
  __syncthreads();

  // ---- out = [decH, ctx] @ outW^T + outb ----
  if (tid < 192) {
    int s = tid / 12, f = tid % 12;
    float acc = outb[f];
    const float4* w4 = (const float4*)(outW + f * 256);
    const float4* d4 = (const float4*)(dh + s * 128);
    const float4* c4 = (const float4*)(a_lds + s * AST);
    #pragma unroll
    for (int k = 0; k < 32; ++k) {
      float4 wv = w4[k], dv = d4[k];
      acc = fmaf(wv.x, dv.x, acc); acc = fmaf(wv.y, dv.y, acc);
      acc = fmaf(wv.z, dv.z, acc); acc = fmaf(wv.w, dv.w, acc);
    }
    #pragma unroll
    for (int k = 0; k < 32; ++k) {
      float4 wv = w4[32 + k], cv = c4[k];
      acc = fmaf(wv.x, cv.x, acc); acc = fmaf(wv.y, cv.y, acc);
      acc = fmaf(wv.z, cv.z, acc); acc = fmaf(wv.w, cv.w, acc);
    }
    out[((size_t)b * TT + s0 + s) * FIN + f] = acc;
  }
}

// ---------------------------------------------------------------------------
extern "C" void kernel_launch(void* const* d_in, const int* in_sizes, int n_in,
                              void* d_out, int out_size, void* d_ws, size_t ws_size,
                              hipStream_t stream)
{
  const float* x     = (const float*)d_in[0];
  const float* eWih  = (const float*)d_in[1];
  const float* eWhh  = (const float*)d_in[2];
  const float* eb    = (const float*)d_in[3];
  const float* dWih  = (const float*)d_in[4];
  const float* dWhh  = (const float*)d_in[5];
  const float* db    = (const float*)d_in[6];
  const float* attnW = (const float*)d_in[7];
  const float* attnb = (const float*)d_in[8];
  const float* vw    = (const float*)d_in[9];
  const float* outW  = (const float*)d_in[10];
  const float* outb  = (const float*)d_in[11];
  float* out = (float*)d_out;

  float* ws   = (float*)d_ws;
  const size_t SEG = (size_t)BB * TT * HH;  // 1,048,576 floats = 4 MB
  float* encH = ws;
  float* decH = ws + SEG;
  float* Abuf = ws + 2 * SEG;
  float* Pbuf = ws + 3 * SEG;

  lstm_kernel<<<64, 1024, 0, stream>>>(x, eWih, eWhh, eb, dWih, dWhh, db, encH, decH);
  proj_kernel<<<1024, 256, 0, stream>>>(encH, decH, attnW, attnb, Abuf, Pbuf);
  attn_kernel<<<512, 512, 0, stream>>>(encH, decH, Abuf, Pbuf, vw, outW, outb, out);
}